// Round 1
// baseline (1050.470 us; speedup 1.0000x reference)
//
#include <hip/hip_runtime.h>

// SparseProductLayer: out = ((x @ M2^T) @ M1^T) @ M0^T + bias
// Each M given as COO (rows, cols, vals), D x D, duplicates sum.
// spmm_t semantics: out[b, rows[e]] += res[b, cols[e]] * vals[e]
// Feature mixing is per-batch-row -> fuse all 3 passes in one kernel,
// each block owns RPB batch rows in LDS ping-pong buffers.

#define BATCH 4096
#define DIM   2048
#define NNZ   16384
#define RPB   4     // batch rows per block (amortizes index loads)
#define NT    256   // threads per block

__global__ __launch_bounds__(NT) void sparse_fused_kernel(
    const float* __restrict__ x,
    const int* __restrict__ rows0, const int* __restrict__ cols0, const float* __restrict__ vals0,
    const int* __restrict__ rows1, const int* __restrict__ cols1, const float* __restrict__ vals1,
    const int* __restrict__ rows2, const int* __restrict__ cols2, const float* __restrict__ vals2,
    const float* __restrict__ bias,
    float* __restrict__ out)
{
    __shared__ float bufA[RPB * DIM];
    __shared__ float bufB[RPB * DIM];

    const int tid  = threadIdx.x;
    const int row0 = blockIdx.x * RPB;

    // Stage RPB rows of x into bufA (vectorized float4, coalesced).
    for (int k = 0; k < RPB; ++k) {
        const float4* src = (const float4*)(x + (size_t)(row0 + k) * DIM);
        float4* dst = (float4*)(&bufA[k * DIM]);
        #pragma unroll 2
        for (int j = tid; j < DIM / 4; j += NT) dst[j] = src[j];
    }

    float* cur = bufA;
    float* acc = bufB;

    // Reference applies matrix 2 first, then 1, then 0.
    const int*   rs[3] = {rows2, rows1, rows0};
    const int*   cs[3] = {cols2, cols1, cols0};
    const float* vs[3] = {vals2, vals1, vals0};

    for (int p = 0; p < 3; ++p) {
        // Zero the accumulator buffer.
        float4* az = (float4*)acc;
        for (int j = tid; j < RPB * DIM / 4; j += NT)
            az[j] = make_float4(0.f, 0.f, 0.f, 0.f);
        __syncthreads();

        const int*   rr = rs[p];
        const int*   cc = cs[p];
        const float* vv = vs[p];

        // COO scatter: acc[k][r] += v * cur[k][c] for each nnz, each of RPB rows.
        for (int e = tid; e < NNZ; e += NT) {
            const int   r = rr[e];
            const int   c = cc[e];
            const float v = vv[e];
            #pragma unroll
            for (int k = 0; k < RPB; ++k) {
                atomicAdd(&acc[k * DIM + r], v * cur[k * DIM + c]);
            }
        }
        __syncthreads();

        // Swap ping-pong buffers.
        float* t = cur; cur = acc; acc = t;
    }

    // Epilogue: out = cur + bias (vectorized, coalesced).
    for (int k = 0; k < RPB; ++k) {
        float4* dst = (float4*)(out + (size_t)(row0 + k) * DIM);
        const float4* src = (const float4*)(cur + k * DIM);
        #pragma unroll 2
        for (int j = tid; j < DIM / 4; j += NT) {
            float4 s  = src[j];
            float4 b4 = ((const float4*)bias)[j];
            s.x += b4.x; s.y += b4.y; s.z += b4.z; s.w += b4.w;
            dst[j] = s;
        }
    }
}

extern "C" void kernel_launch(void* const* d_in, const int* in_sizes, int n_in,
                              void* d_out, int out_size, void* d_ws, size_t ws_size,
                              hipStream_t stream) {
    const float* x     = (const float*)d_in[0];
    const int*   rows0 = (const int*)  d_in[1];
    const int*   cols0 = (const int*)  d_in[2];
    const float* vals0 = (const float*)d_in[3];
    const int*   rows1 = (const int*)  d_in[4];
    const int*   cols1 = (const int*)  d_in[5];
    const float* vals1 = (const float*)d_in[6];
    const int*   rows2 = (const int*)  d_in[7];
    const int*   cols2 = (const int*)  d_in[8];
    const float* vals2 = (const float*)d_in[9];
    const float* bias  = (const float*)d_in[10];
    float* out = (float*)d_out;

    dim3 grid(BATCH / RPB);
    dim3 block(NT);
    hipLaunchKernelGGL(sparse_fused_kernel, grid, block, 0, stream,
                       x, rows0, cols0, vals0,
                       rows1, cols1, vals1,
                       rows2, cols2, vals2,
                       bias, out);
}

// Round 2
// 115.003 us; speedup vs baseline: 9.1343x; 9.1343x over previous
//
#include <hip/hip_runtime.h>

// SparseProductLayer rewrite:
//   out = x @ (M0*M1*M2)^T + bias
// Build Mc = M0*M1*M2 dense (2048x2048) on device each launch, then one
// bf16-MFMA GEMM (fp32 accumulate). Threshold is 4.44 absolute; bf16
// rounding error ~1.
//
// d_ws layout (bytes):
//   [0)            T      f32 [D][D]    16777216
//   [16777216)     Mc     bf16 [D][D]    8388608
//   [25165824)     Xb     bf16 [B][D]   16777216
//   [41943040)     CSR arrays (M2 and M0)        ~295 KB

#define BATCH 4096
#define DIM   2048
#define NNZc  16384
#define NT    256

typedef short bf16x8 __attribute__((ext_vector_type(8)));
typedef float f32x4  __attribute__((ext_vector_type(4)));

__device__ __forceinline__ unsigned short f2bf(float f) {
    unsigned u = __float_as_uint(f);
    unsigned r = (u + 0x7fffu + ((u >> 16) & 1u)) >> 16;   // RNE
    return (unsigned short)r;
}

// ---- CSR build: histogram ----
__global__ void hist_kernel(const int* __restrict__ rows2, const int* __restrict__ rows0,
                            int* __restrict__ cur2, int* __restrict__ cur0) {
    int e = blockIdx.x * NT + threadIdx.x;
    if (e < NNZc)       atomicAdd(&cur2[rows2[e]], 1);
    else                atomicAdd(&cur0[rows0[e - NNZc]], 1);
}

// ---- CSR build: exclusive scan of 2048 counts (one block per matrix) ----
__global__ void scan_kernel(int* cur2, int* off2, int* cur0, int* off0) {
    int* cur = blockIdx.x ? cur0 : cur2;
    int* off = blockIdx.x ? off0 : off2;
    __shared__ int part[NT];
    int t = threadIdx.x;
    int c[8]; int s = 0;
    #pragma unroll
    for (int i = 0; i < 8; ++i) { c[i] = cur[t * 8 + i]; s += c[i]; }
    part[t] = s;
    __syncthreads();
    if (t == 0) {
        int run = 0;
        for (int i = 0; i < NT; ++i) { int v = part[i]; part[i] = run; run += v; }
    }
    __syncthreads();
    int base = part[t];
    #pragma unroll
    for (int i = 0; i < 8; ++i) {
        int idx = t * 8 + i;
        off[idx] = base; cur[idx] = base; base += c[i];
    }
    if (t == 0) off[DIM] = NNZc;
}

// ---- CSR build: scatter entries into row buckets ----
__global__ void scatter_kernel(const int* __restrict__ rows2, const int* __restrict__ cols2,
                               const float* __restrict__ vals2,
                               const int* __restrict__ rows0, const int* __restrict__ cols0,
                               const float* __restrict__ vals0,
                               int* cur2, int* __restrict__ col2, float* __restrict__ val2,
                               int* cur0, int* __restrict__ col0, float* __restrict__ val0) {
    int e = blockIdx.x * NT + threadIdx.x;
    if (e < NNZc) {
        int slot = atomicAdd(&cur2[rows2[e]], 1);
        col2[slot] = cols2[e]; val2[slot] = vals2[e];
    } else {
        int e0 = e - NNZc;
        int slot = atomicAdd(&cur0[rows0[e0]], 1);
        col0[slot] = cols0[e0]; val0[slot] = vals0[e0];
    }
}

// ---- T = M1 * M2 (dense f32 accumulate via global atomics; ~131K ops) ----
__global__ void tbuild_kernel(const int* __restrict__ rows1, const int* __restrict__ cols1,
                              const float* __restrict__ vals1,
                              const int* __restrict__ off2, const int* __restrict__ col2,
                              const float* __restrict__ val2,
                              float* __restrict__ T) {
    int e = blockIdx.x * NT + threadIdx.x;
    if (e >= NNZc) return;
    int   r1 = rows1[e];
    int   c1 = cols1[e];
    float v1 = vals1[e];
    int b = off2[c1], en = off2[c1 + 1];
    for (int i = b; i < en; ++i)
        atomicAdd(&T[(size_t)r1 * DIM + col2[i]], v1 * val2[i]);
}

// ---- Mc[r,:] = sum_{entries (c0,v0) in M0 row r} v0 * T[c0,:]  -> bf16 ----
__global__ __launch_bounds__(NT) void rowgather_kernel(
        const int* __restrict__ off0, const int* __restrict__ col0,
        const float* __restrict__ val0,
        const float* __restrict__ T, unsigned short* __restrict__ Mc) {
    int r = blockIdx.x;
    int b = off0[r], e = off0[r + 1];
    __shared__ int   sc[64];
    __shared__ float sv[64];
    int tid = threadIdx.x;
    float acc[8] = {0.f, 0.f, 0.f, 0.f, 0.f, 0.f, 0.f, 0.f};
    for (int cb = b; cb < e; cb += 64) {
        int n = min(64, e - cb);
        if (tid < n) { sc[tid] = col0[cb + tid]; sv[tid] = val0[cb + tid]; }
        __syncthreads();
        for (int i = 0; i < n; ++i) {
            const float* Trow = T + (size_t)sc[i] * DIM;
            float v = sv[i];
            #pragma unroll
            for (int jj = 0; jj < 8; ++jj)
                acc[jj] += v * Trow[tid + jj * NT];
        }
        __syncthreads();
    }
    #pragma unroll
    for (int jj = 0; jj < 8; ++jj)
        Mc[(size_t)r * DIM + tid + jj * NT] = f2bf(acc[jj]);
}

// ---- x (f32) -> bf16 ----
__global__ void xconv_kernel(const float* __restrict__ x, unsigned short* __restrict__ Xb) {
    size_t i = ((size_t)blockIdx.x * NT + threadIdx.x) * 8;
    float4 a = *(const float4*)(x + i);
    float4 b = *(const float4*)(x + i + 4);
    unsigned short o[8] = {f2bf(a.x), f2bf(a.y), f2bf(a.z), f2bf(a.w),
                           f2bf(b.x), f2bf(b.y), f2bf(b.z), f2bf(b.w)};
    *(ulonglong2*)(Xb + i) = *(ulonglong2*)o;
}

// ---- GEMM: C(4096x2048) = Xb @ Mc^T + bias, bf16 MFMA, m97-style 128^2 tile ----
#define TM 128
#define TN 128
#define TK 32
__global__ __launch_bounds__(256) void gemm_bt(
        const unsigned short* __restrict__ A,   // Xb  [BATCH][DIM] bf16
        const unsigned short* __restrict__ Bm,  // Mc  [DIM][DIM]  bf16
        const float* __restrict__ bias,
        float* __restrict__ C) {
    __shared__ unsigned short As[TM * TK];   // [128][32], row stride 64 B
    __shared__ unsigned short Bs[TN * TK];
    const int tid = threadIdx.x;
    const int l = tid & 63, w = tid >> 6;
    const int wm = w & 1, wn = w >> 1;       // 2x2 wave grid
    const int tileM = blockIdx.y * TM;
    const int tileN = blockIdx.x * TN;
    const int K = DIM;
    f32x4 acc[4][4] = {};

    for (int k0 = 0; k0 < K; k0 += TK) {
        #pragma unroll
        for (int q = 0; q < 2; ++q) {
            int f = q * 256 + tid;
            int row = f >> 2, seg = f & 3;
            const unsigned short* ga = A  + (size_t)(tileM + row) * K + k0 + seg * 8;
            const unsigned short* gb = Bm + (size_t)(tileN + row) * K + k0 + seg * 8;
            char* la = (char*)As + (q * 256 + w * 64) * 16;   // wave-uniform base
            char* lb = (char*)Bs + (q * 256 + w * 64) * 16;
            __builtin_amdgcn_global_load_lds(
                (const __attribute__((address_space(1))) void*)ga,
                (__attribute__((address_space(3))) void*)la, 16, 0, 0);
            __builtin_amdgcn_global_load_lds(
                (const __attribute__((address_space(1))) void*)gb,
                (__attribute__((address_space(3))) void*)lb, 16, 0, 0);
        }
        __syncthreads();
        bf16x8 af[4], bfr[4];
        #pragma unroll
        for (int i = 0; i < 4; ++i) {
            int ra = wm * 64 + i * 16 + (l & 15);
            af[i]  = *(const bf16x8*)((const char*)As + ra * 64 + (l >> 4) * 16);
            int rb = wn * 64 + i * 16 + (l & 15);
            bfr[i] = *(const bf16x8*)((const char*)Bs + rb * 64 + (l >> 4) * 16);
        }
        #pragma unroll
        for (int i = 0; i < 4; ++i)
            #pragma unroll
            for (int j = 0; j < 4; ++j)
                acc[i][j] = __builtin_amdgcn_mfma_f32_16x16x32_bf16(af[i], bfr[j], acc[i][j], 0, 0, 0);
        __syncthreads();
    }

    #pragma unroll
    for (int j = 0; j < 4; ++j) {
        int col = tileN + wn * 64 + j * 16 + (l & 15);
        float bj = bias[col];
        #pragma unroll
        for (int i = 0; i < 4; ++i) {
            int rw = tileM + wm * 64 + i * 16 + (l >> 4) * 4;
            #pragma unroll
            for (int r = 0; r < 4; ++r)
                C[(size_t)(rw + r) * DIM + col] = acc[i][j][r] + bj;
        }
    }
}

extern "C" void kernel_launch(void* const* d_in, const int* in_sizes, int n_in,
                              void* d_out, int out_size, void* d_ws, size_t ws_size,
                              hipStream_t stream) {
    const float* x     = (const float*)d_in[0];
    const int*   rows0 = (const int*)  d_in[1];
    const int*   cols0 = (const int*)  d_in[2];
    const float* vals0 = (const float*)d_in[3];
    const int*   rows1 = (const int*)  d_in[4];
    const int*   cols1 = (const int*)  d_in[5];
    const float* vals1 = (const float*)d_in[6];
    const int*   rows2 = (const int*)  d_in[7];
    const int*   cols2 = (const int*)  d_in[8];
    const float* vals2 = (const float*)d_in[9];
    const float* bias  = (const float*)d_in[10];
    float* out = (float*)d_out;

    char* ws = (char*)d_ws;
    float*          T   = (float*)ws;                              // 16 MB
    unsigned short* Mc  = (unsigned short*)(ws + 16777216);        // 8 MB
    unsigned short* Xb  = (unsigned short*)(ws + 25165824);        // 16 MB
    int* csr = (int*)(ws + 41943040);
    int*   off2 = csr;             // 2052
    int*   cur2 = off2 + 2052;     // 2048
    int*   col2 = cur2 + 2048;     // 16384
    float* val2 = (float*)(col2 + NNZc);
    int*   off0 = (int*)(val2 + NNZc);
    int*   cur0 = off0 + 2052;
    int*   col0 = cur0 + 2048;
    float* val0 = (float*)(col0 + NNZc);
    size_t csr_bytes = (size_t)4 * (2052 + 2048 + NNZc * 2) * 2;

    hipMemsetAsync(T, 0, (size_t)DIM * DIM * 4, stream);
    hipMemsetAsync(csr, 0, csr_bytes, stream);

    hist_kernel<<<2 * NNZc / NT, NT, 0, stream>>>(rows2, rows0, cur2, cur0);
    scan_kernel<<<2, NT, 0, stream>>>(cur2, off2, cur0, off0);
    scatter_kernel<<<2 * NNZc / NT, NT, 0, stream>>>(rows2, cols2, vals2, rows0, cols0, vals0,
                                                     cur2, col2, val2, cur0, col0, val0);
    tbuild_kernel<<<NNZc / NT, NT, 0, stream>>>(rows1, cols1, vals1, off2, col2, val2, T);
    rowgather_kernel<<<DIM, NT, 0, stream>>>(off0, col0, val0, T, Mc);
    xconv_kernel<<<(BATCH * DIM) / (NT * 8), NT, 0, stream>>>(x, Xb);

    dim3 ggrid(DIM / TN, BATCH / TM);
    gemm_bt<<<ggrid, 256, 0, stream>>>(Xb, Mc, bias, out);
}

// Round 3
// 94.370 us; speedup vs baseline: 11.1314x; 1.2186x over previous
//
#include <hip/hip_runtime.h>

// SparseProductLayer:
//   out = x @ (M0*M1*M2)^T + bias
// Round 3: build Mc = M0*M1*M2 ENTRY-WISE (3-level CSR tree walk, ~1M scalar
// FMAs in LDS) -- no dense intermediate T, no 16MB memset, no global atomics.
// Then one bf16-MFMA GEMM (verified m97-style 128^2 tile, fp32 accumulate).
//
// d_ws layout (bytes):
//   [0)         Mc  bf16 [D][D]     8388608
//   [8388608)   Xb  bf16 [B][D]    16777216
//   [25165824)  CSR arrays (M0,M1,M2): off[3][2052] cur[3][2048] col[3][16384] val[3][16384]

#define BATCH 4096
#define DIM   2048
#define NNZc  16384
#define NT    256

typedef short bf16x8 __attribute__((ext_vector_type(8)));
typedef float f32x4  __attribute__((ext_vector_type(4)));

__device__ __forceinline__ unsigned short f2bf(float f) {
    unsigned u = __float_as_uint(f);
    unsigned r = (u + 0x7fffu + ((u >> 16) & 1u)) >> 16;   // RNE
    return (unsigned short)r;
}

// ---- CSR build: histogram (all 3 matrices in one launch) ----
__global__ void hist_kernel(const int* __restrict__ rows0, const int* __restrict__ rows1,
                            const int* __restrict__ rows2, int* __restrict__ cur) {
    int e = blockIdx.x * NT + threadIdx.x;          // 0 .. 3*NNZ
    int m = e >> 14, i = e & (NNZc - 1);
    const int* rp = (m == 0) ? rows0 : (m == 1) ? rows1 : rows2;
    atomicAdd(&cur[m * DIM + rp[i]], 1);
}

// ---- CSR build: exclusive scan of 2048 counts (one block per matrix) ----
__global__ void scan_kernel(int* __restrict__ curb, int* __restrict__ offb) {
    int* cur = curb + blockIdx.x * DIM;
    int* off = offb + blockIdx.x * 2052;
    __shared__ int part[NT];
    int t = threadIdx.x;
    int c[8]; int s = 0;
    #pragma unroll
    for (int i = 0; i < 8; ++i) { c[i] = cur[t * 8 + i]; s += c[i]; }
    part[t] = s;
    __syncthreads();
    if (t == 0) {
        int run = 0;
        for (int i = 0; i < NT; ++i) { int v = part[i]; part[i] = run; run += v; }
    }
    __syncthreads();
    int base = part[t];
    #pragma unroll
    for (int i = 0; i < 8; ++i) {
        int idx = t * 8 + i;
        off[idx] = base; cur[idx] = base; base += c[i];
    }
    if (t == 0) off[DIM] = NNZc;
}

// ---- CSR build: scatter entries into row buckets ----
__global__ void scatter_kernel(const int* __restrict__ rows0, const int* __restrict__ cols0,
                               const float* __restrict__ vals0,
                               const int* __restrict__ rows1, const int* __restrict__ cols1,
                               const float* __restrict__ vals1,
                               const int* __restrict__ rows2, const int* __restrict__ cols2,
                               const float* __restrict__ vals2,
                               int* __restrict__ cur,
                               int* __restrict__ colb, float* __restrict__ valb) {
    int e = blockIdx.x * NT + threadIdx.x;
    int m = e >> 14, i = e & (NNZc - 1);
    const int*   rp = (m == 0) ? rows0 : (m == 1) ? rows1 : rows2;
    const int*   cp = (m == 0) ? cols0 : (m == 1) ? cols1 : cols2;
    const float* vp = (m == 0) ? vals0 : (m == 1) ? vals1 : vals2;
    int slot = atomicAdd(&cur[m * DIM + rp[i]], 1);
    colb[m * NNZc + slot] = cp[i];
    valb[m * NNZc + slot] = vp[i];
}

// ---- Mc build: per block, RPB output rows via 3-level tree walk in LDS ----
#define RPB  2
#define PCAP 2048
__global__ __launch_bounds__(NT) void mcbuild_kernel(
        const int* __restrict__ offb, const int* __restrict__ colb,
        const float* __restrict__ valb, unsigned short* __restrict__ Mc) {
    const int* off0 = offb;              const int* off1 = offb + 2052;  const int* off2 = offb + 4104;
    const int* col0 = colb;              const int* col1 = colb + NNZc;  const int* col2 = colb + 2 * NNZc;
    const float* val0 = valb;            const float* val1 = valb + NNZc; const float* val2 = valb + 2 * NNZc;

    __shared__ float acc[RPB * DIM];     // 16 KB
    __shared__ int   pk[PCAP];           // 8 KB: (k<<16)|c1
    __shared__ float pw[PCAP];           // 8 KB
    __shared__ int   npairs;

    const int tid = threadIdx.x;
    const int r0  = blockIdx.x * RPB;

    f32x4* az = (f32x4*)acc;
    #pragma unroll
    for (int j = tid; j < RPB * DIM / 4; j += NT) az[j] = (f32x4){0.f, 0.f, 0.f, 0.f};
    if (tid == 0) npairs = 0;
    __syncthreads();

    // Expand (M0 row r0+k) x (M1) into pair list (k, c1, w=v0*v1).
    #pragma unroll
    for (int k = 0; k < RPB; ++k) {
        int b = off0[r0 + k], e = off0[r0 + k + 1];
        for (int i = b + tid; i < e; i += NT) {
            int   c0 = col0[i];
            float v0 = val0[i];
            int b1 = off1[c0], e1 = off1[c0 + 1];
            for (int j = b1; j < e1; ++j) {
                float w = v0 * val1[j];
                int   c1 = col1[j];
                int slot = atomicAdd(&npairs, 1);
                if (slot < PCAP) { pk[slot] = (k << 16) | c1; pw[slot] = w; }
                else {  // overflow fallback (statistically never): process inline
                    int b2 = off2[c1], e2 = off2[c1 + 1];
                    for (int q = b2; q < e2; ++q)
                        atomicAdd(&acc[k * DIM + col2[q]], w * val2[q]);
                }
            }
        }
    }
    __syncthreads();

    // Drain pair list: acc[k][c2] += w * v2 over M2 row c1.
    int np = min(npairs, PCAP);
    for (int p = tid; p < np; p += NT) {
        int   k  = pk[p] >> 16, c1 = pk[p] & 0xffff;
        float w  = pw[p];
        int b2 = off2[c1], e2 = off2[c1 + 1];
        for (int q = b2; q < e2; ++q)
            atomicAdd(&acc[k * DIM + col2[q]], w * val2[q]);
    }
    __syncthreads();

    // Write Mc rows as bf16 (vectorized 16B stores).
    #pragma unroll
    for (int k = 0; k < RPB; ++k) {
        unsigned short o[8];
        #pragma unroll
        for (int jj = 0; jj < 8; ++jj) o[jj] = f2bf(acc[k * DIM + tid * 8 + jj]);
        *(ulonglong2*)(Mc + (size_t)(r0 + k) * DIM + tid * 8) = *(ulonglong2*)o;
    }
}

// ---- x (f32) -> bf16 ----
__global__ void xconv_kernel(const float* __restrict__ x, unsigned short* __restrict__ Xb) {
    size_t i = ((size_t)blockIdx.x * NT + threadIdx.x) * 8;
    float4 a = *(const float4*)(x + i);
    float4 b = *(const float4*)(x + i + 4);
    unsigned short o[8] = {f2bf(a.x), f2bf(a.y), f2bf(a.z), f2bf(a.w),
                           f2bf(b.x), f2bf(b.y), f2bf(b.z), f2bf(b.w)};
    *(ulonglong2*)(Xb + i) = *(ulonglong2*)o;
}

// ---- GEMM: C(4096x2048) = Xb @ Mc^T + bias, bf16 MFMA, m97-style 128^2 tile ----
#define TM 128
#define TN 128
#define TK 32
__global__ __launch_bounds__(256) void gemm_bt(
        const unsigned short* __restrict__ A,   // Xb  [BATCH][DIM] bf16
        const unsigned short* __restrict__ Bm,  // Mc  [DIM][DIM]  bf16
        const float* __restrict__ bias,
        float* __restrict__ C) {
    __shared__ unsigned short As[TM * TK];   // [128][32], row stride 64 B
    __shared__ unsigned short Bs[TN * TK];
    const int tid = threadIdx.x;
    const int l = tid & 63, w = tid >> 6;
    const int wm = w & 1, wn = w >> 1;       // 2x2 wave grid
    const int tileM = blockIdx.y * TM;
    const int tileN = blockIdx.x * TN;
    const int K = DIM;
    f32x4 acc[4][4] = {};

    for (int k0 = 0; k0 < K; k0 += TK) {
        #pragma unroll
        for (int q = 0; q < 2; ++q) {
            int f = q * 256 + tid;
            int row = f >> 2, seg = f & 3;
            const unsigned short* ga = A  + (size_t)(tileM + row) * K + k0 + seg * 8;
            const unsigned short* gb = Bm + (size_t)(tileN + row) * K + k0 + seg * 8;
            char* la = (char*)As + (q * 256 + w * 64) * 16;   // wave-uniform base
            char* lb = (char*)Bs + (q * 256 + w * 64) * 16;
            __builtin_amdgcn_global_load_lds(
                (const __attribute__((address_space(1))) void*)ga,
                (__attribute__((address_space(3))) void*)la, 16, 0, 0);
            __builtin_amdgcn_global_load_lds(
                (const __attribute__((address_space(1))) void*)gb,
                (__attribute__((address_space(3))) void*)lb, 16, 0, 0);
        }
        __syncthreads();
        bf16x8 af[4], bfr[4];
        #pragma unroll
        for (int i = 0; i < 4; ++i) {
            int ra = wm * 64 + i * 16 + (l & 15);
            af[i]  = *(const bf16x8*)((const char*)As + ra * 64 + (l >> 4) * 16);
            int rb = wn * 64 + i * 16 + (l & 15);
            bfr[i] = *(const bf16x8*)((const char*)Bs + rb * 64 + (l >> 4) * 16);
        }
        #pragma unroll
        for (int i = 0; i < 4; ++i)
            #pragma unroll
            for (int j = 0; j < 4; ++j)
                acc[i][j] = __builtin_amdgcn_mfma_f32_16x16x32_bf16(af[i], bfr[j], acc[i][j], 0, 0, 0);
        __syncthreads();
    }

    #pragma unroll
    for (int j = 0; j < 4; ++j) {
        int col = tileN + wn * 64 + j * 16 + (l & 15);
        float bj = bias[col];
        #pragma unroll
        for (int i = 0; i < 4; ++i) {
            int rw = tileM + wm * 64 + i * 16 + (l >> 4) * 4;
            #pragma unroll
            for (int r = 0; r < 4; ++r)
                C[(size_t)(rw + r) * DIM + col] = acc[i][j][r] + bj;
        }
    }
}

extern "C" void kernel_launch(void* const* d_in, const int* in_sizes, int n_in,
                              void* d_out, int out_size, void* d_ws, size_t ws_size,
                              hipStream_t stream) {
    const float* x     = (const float*)d_in[0];
    const int*   rows0 = (const int*)  d_in[1];
    const int*   cols0 = (const int*)  d_in[2];
    const float* vals0 = (const float*)d_in[3];
    const int*   rows1 = (const int*)  d_in[4];
    const int*   cols1 = (const int*)  d_in[5];
    const float* vals1 = (const float*)d_in[6];
    const int*   rows2 = (const int*)  d_in[7];
    const int*   cols2 = (const int*)  d_in[8];
    const float* vals2 = (const float*)d_in[9];
    const float* bias  = (const float*)d_in[10];
    float* out = (float*)d_out;

    char* ws = (char*)d_ws;
    unsigned short* Mc = (unsigned short*)ws;                 // 8 MB
    unsigned short* Xb = (unsigned short*)(ws + 8388608);     // 16 MB
    int*   offb = (int*)(ws + 25165824);      // 3 * 2052
    int*   curb = offb + 3 * 2052;            // 3 * 2048
    int*   colb = curb + 3 * DIM;             // 3 * 16384
    float* valb = (float*)(colb + 3 * NNZc);  // 3 * 16384

    hipMemsetAsync(curb, 0, 3 * DIM * sizeof(int), stream);

    hist_kernel<<<3 * NNZc / NT, NT, 0, stream>>>(rows0, rows1, rows2, curb);
    scan_kernel<<<3, NT, 0, stream>>>(curb, offb);
    scatter_kernel<<<3 * NNZc / NT, NT, 0, stream>>>(rows0, cols0, vals0,
                                                     rows1, cols1, vals1,
                                                     rows2, cols2, vals2,
                                                     curb, colb, valb);
    mcbuild_kernel<<<DIM / RPB, NT, 0, stream>>>(offb, colb, valb, Mc);
    xconv_kernel<<<(BATCH * DIM) / (NT * 8), NT, 0, stream>>>(x, Xb);

    dim3 ggrid(DIM / TN, BATCH / TM);
    gemm_bt<<<ggrid, 256, 0, stream>>>(Xb, Mc, bias, out);
}